// Round 9
// baseline (146.313 us; speedup 1.0000x reference)
//
#include <hip/hip_runtime.h>
#include <hip/hip_bf16.h>

// Windowed attention smoothing via MFMA — barrier-free, per-wave autonomous.
// v7b = v7 with the glibc name collision fixed: __exp2f -> 
// __builtin_amdgcn_exp2f (v_exp_f32, D = 2^S0). Logic unchanged vs v7:
//   1. grid = n_btiles (one 64-row tile per block). With the 1024-cap,
//      3125 tiles split 4-vs-3 per block -> 8% CU imbalance plus a
//      low-occupancy tail when sibling blocks exit early. Dynamic refill
//      keeps CUs at the 4-block LDS cap until the queue drains.
//   2. tanh via exp2+rcp (kills the 7-op fp32 divide, x16/tile) and
//      softmax exp via exp2 with folded 1/sqrt(64)*log2e constant.
// v6's P4-LDS-broadcast stays REVERTED (it spilled: +20MB scratch writes
// at the compiler's hard 64-VGPR allocation).
// No __syncthreads: LDS regions are wave-private; DS pipe is in-order
// within a wave.
//
// rows=200000, RANK=64, WINDOW=11. Block=256 (4 waves), 16 rows/wave/tile.

constexpr int RANK   = 64;
constexpr int WINDOW = 11;
constexpr int PAD    = 5;
constexpr int TILE   = 16;   // rows per wave
constexpr int BLOCK  = 256;  // 4 waves
constexpr int TR     = 64;   // rows per block-tile
constexpr int BROWS  = 28;   // staged band rows (rw-5 .. rw+22)
constexpr int BSTR   = 68;   // band row stride (floats): 272B, 16B-aligned
constexpr int SC_S   = 18;   // f32 elems per Sc row (breaks pow2)

constexpr int BAND_F = BROWS * BSTR;            // 1904 floats per wave
constexpr int SC_OFF = 4 * BAND_F;              // 7616
constexpr int SMEMF  = SC_OFF + 4 * 32 * SC_S;  // 9920 floats = 39680 B

typedef short short8  __attribute__((ext_vector_type(8)));
typedef float float4v __attribute__((ext_vector_type(4)));

__device__ __forceinline__ short8 cvt_bf8(float4 a, float4 b) {
    union { short8 s; __hip_bfloat162 h[4]; } u;
    u.h[0] = __float22bfloat162_rn(make_float2(a.x, a.y));
    u.h[1] = __float22bfloat162_rn(make_float2(a.z, a.w));
    u.h[2] = __float22bfloat162_rn(make_float2(b.x, b.y));
    u.h[3] = __float22bfloat162_rn(make_float2(b.z, b.w));
    return u.s;
}

__device__ __forceinline__ float fast_tanh(float x) {
    // tanh(x) = 1 - 2/(1+e^{2x});  e^{2x} = 2^{(2*log2 e)*x}
    const float e = __builtin_amdgcn_exp2f(2.8853900817779268f * x);
    return 1.0f - 2.0f * __builtin_amdgcn_rcpf(1.0f + e);
}

__global__ __launch_bounds__(BLOCK)
__attribute__((amdgpu_waves_per_eu(4, 4)))
void attn_win_kernel(
    const float* __restrict__ A,   // (rows, 64)
    const float* __restrict__ W,   // (64, 64) row-major (out,in)
    const float* __restrict__ b,   // (64,)
    float* __restrict__ out,       // (rows, 64)
    int rows)
{
    // Flat LDS so the deliberate band-row over-reads (rows 28..31, dead
    // data) stay in-bounds of the block allocation.
    __shared__ __align__(16) float smem[SMEMF];

    const int lane = threadIdx.x & 63;
    const int wv   = threadIdx.x >> 6;
    const int m16  = lane & 15;
    const int quad = lane >> 4;
    const int sr   = lane >> 4;        // staging: row within group-of-4
    const int sc4  = (lane & 15) * 4;  // staging: col base (float4)

    float* const bandW = smem + wv * BAND_F;                 // [28][68]
    float* const ScW   = smem + SC_OFF + wv * 32 * SC_S;     // [32][18]

    // ---- Persistent W fragments (32 VGPRs) + transposed bias, loaded ONCE ----
    short8 wfrag[4][2];  // [ct][kf]: W[ct*16+m16][kf*32 + quad*8 + j]
    #pragma unroll
    for (int ct = 0; ct < 4; ct++) {
        #pragma unroll
        for (int kf = 0; kf < 2; kf++) {
            const float4* p =
                (const float4*)(W + (ct * 16 + m16) * RANK + kf * 32 + quad * 8);
            wfrag[ct][kf] = cvt_bf8(p[0], p[1]);
        }
    }
    float4 biasT[4];
    #pragma unroll
    for (int ct = 0; ct < 4; ct++)
        biasT[ct] = *(const float4*)(b + ct * 16 + quad * 4);

    // bpermute source-lane indices (byte units): word w of B-frag comes from
    // lane m16 + 16*(2*(quad&1) + (w>>1)).
    const int idxA = 4 * m16 + 128 * (quad & 1);
    const int idxB = idxA + 64;

    const int n_btiles = (rows + TR - 1) / TR;
    int bt = blockIdx.x;
    if (bt >= n_btiles) return;

    // ---- prologue: stage FIRST tile's 28-row fp32 band (guarded) ----
    {
        const int rw0 = bt * TR + wv * TILE;
        #pragma unroll
        for (int ro = 0; ro < 7; ro++) {
            const int g = rw0 - PAD + ro * 4 + sr;
            float4 x = make_float4(0.f, 0.f, 0.f, 0.f);
            if ((unsigned)g < (unsigned)rows)
                x = *(const float4*)(A + (size_t)g * RANK + sc4);
            *(float4*)&bandW[(ro * 4 + sr) * BSTR + sc4] = x;
        }
    }

    for (; bt < n_btiles; bt += gridDim.x) {
        const int rw = bt * TR + wv * TILE;   // this wave's rows rw..rw+15

        // ---- am1 frags from band (fp32 -> bf16): A rows rw+m16 ----
        short8 am1[2];
        #pragma unroll
        for (int kf = 0; kf < 2; kf++) {
            const float4* pp =
                (const float4*)&bandW[(PAD + m16) * BSTR + kf * 32 + quad * 8];
            am1[kf] = cvt_bf8(pp[0], pp[1]);
        }

        // ---- M1 (transposed): accT[ct] = W-block(ct) x A^T + b ----
        // C element: v1[m = m16][n = ct*16 + quad*4 + r]
        float4v accT[4];
        #pragma unroll
        for (int ct = 0; ct < 4; ct++)
            accT[ct] = (float4v){biasT[ct].x, biasT[ct].y,
                                 biasT[ct].z, biasT[ct].w};
        #pragma unroll
        for (int kf = 0; kf < 2; kf++)
            #pragma unroll
            for (int ct = 0; ct < 4; ct++)
                accT[ct] = __builtin_amdgcn_mfma_f32_16x16x32_bf16(
                    wfrag[ct][kf], am1[kf], accT[ct], 0, 0, 0);

        // ---- tanh + pack to bf16 pairs ----
        int pk[4][2];
        #pragma unroll
        for (int ct = 0; ct < 4; ct++)
            #pragma unroll
            for (int u = 0; u < 2; u++) {
                union { __hip_bfloat162 h; int i; } cv;
                cv.h = __float22bfloat162_rn(make_float2(
                    fast_tanh(accT[ct][2 * u]),
                    fast_tanh(accT[ct][2 * u + 1])));
                pk[ct][u] = cv.i;
            }

        // ---- M2 B-frag gather via ds_bpermute (no LDS storage) ----
        short8 bfr[2];
        #pragma unroll
        for (int kf = 0; kf < 2; kf++) {
            union { int w[4]; short8 s; } u;
            #pragma unroll
            for (int w = 0; w < 4; w++) {
                const int idx = (w >> 1) ? idxB : idxA;
                const int lo = __builtin_amdgcn_ds_bpermute(idx, pk[2 * kf][w & 1]);
                const int hi = __builtin_amdgcn_ds_bpermute(idx, pk[2 * kf + 1][w & 1]);
                u.w[w] = (quad >= 2) ? hi : lo;
            }
            bfr[kf] = u.s;
        }

        // ---- abnd frags: band rows it*16+m16 (rows 28..31 are dead reads) ----
        short8 abnd[2][2];
        #pragma unroll
        for (int it = 0; it < 2; it++)
            #pragma unroll
            for (int kf = 0; kf < 2; kf++) {
                const float4* pp = (const float4*)
                    &bandW[(it * 16 + m16) * BSTR + kf * 32 + quad * 8];
                abnd[it][kf] = cvt_bf8(pp[0], pp[1]);
            }

        // ---- issue NEXT tile's stage loads EARLY (cover under M2+softmax).
        //      With grid = n_btiles these are all OOB -> exec-masked skip. ----
        float4 stg[7];
        {
            const int rwn = rw + (int)gridDim.x * TR;
            #pragma unroll
            for (int ro = 0; ro < 7; ro++) {
                const int g = rwn - PAD + ro * 4 + sr;
                stg[ro] = make_float4(0.f, 0.f, 0.f, 0.f);
                if ((unsigned)g < (unsigned)rows)
                    stg[ro] = *(const float4*)(A + (size_t)g * RANK + sc4);
            }
        }

        // ---- M2: S[i][q] = dot(band[i], v1[q]) ----
        float4v sacc[2];
        sacc[0] = (float4v){0.f, 0.f, 0.f, 0.f};
        sacc[1] = (float4v){0.f, 0.f, 0.f, 0.f};
        #pragma unroll
        for (int kf = 0; kf < 2; kf++)
            #pragma unroll
            for (int it = 0; it < 2; it++)
                sacc[it] = __builtin_amdgcn_mfma_f32_16x16x32_bf16(
                    abnd[it][kf], bfr[kf], sacc[it], 0, 0, 0);

        // scatter S (i = it*16+quad*4+rg, q = m16); rows 26..31 are dead
        #pragma unroll
        for (int it = 0; it < 2; it++)
            #pragma unroll
            for (int rg = 0; rg < 4; rg++)
                ScW[(it * 16 + quad * 4 + rg) * SC_S + m16] = sacc[it][rg];

        // ---- softmax over band i in [q, q+10] of column q=m16 ----
        // (redundant across quads; lane rr<16 holds row rw+rr's probs)
        float p[WINDOW];
        {
            float s[WINDOW];
            float mx = -1e30f;
            #pragma unroll
            for (int w = 0; w < WINDOW; w++) {
                s[w] = ScW[(m16 + w) * SC_S + m16];
                mx = fmaxf(mx, s[w]);
            }
            float den = 0.0f;
            #pragma unroll
            for (int w = 0; w < WINDOW; w++) {
                // exp((s-mx)/8) = 2^((s-mx) * 0.125*log2 e)
                p[w] = __builtin_amdgcn_exp2f(
                    (s[w] - mx) * 0.18033688011112042f);
                den += p[w];
            }
            const float rden = __fdividef(1.0f, den);
            #pragma unroll
            for (int w = 0; w < WINDOW; w++) p[w] *= rden;
        }

        // ---- aw: fp32 window, last reads of the current band ----
        float aw[26];
        #pragma unroll
        for (int s = 0; s < 26; s++) aw[s] = bandW[s * BSTR + lane];

        // ---- overwrite band with NEXT tile's rows (DS in-order per wave) ----
        #pragma unroll
        for (int ro = 0; ro < 7; ro++)
            *(float4*)&bandW[(ro * 4 + sr) * BSTR + sc4] = stg[ro];

        // ---- P4: out[rw+rr][lane] = sum_w p[rr][w] * aw[rr+w] ----
        #pragma unroll
        for (int rr = 0; rr < TILE; rr++) {
            float o = 0.0f;
            #pragma unroll
            for (int w = 0; w < WINDOW; w++) {
                const float pw = __uint_as_float(
                    __builtin_amdgcn_readlane(__float_as_uint(p[w]), rr));
                o = fmaf(pw, aw[rr + w], o);
            }
            if (rw + rr < rows)   // wave-uniform scalar guard
                out[(size_t)(rw + rr) * RANK + lane] = o;
        }
    }
}

extern "C" void kernel_launch(void* const* d_in, const int* in_sizes, int n_in,
                              void* d_out, int out_size, void* d_ws, size_t ws_size,
                              hipStream_t stream) {
    const float* A = (const float*)d_in[0];
    const float* W = (const float*)d_in[1];
    const float* b = (const float*)d_in[2];
    float* out = (float*)d_out;

    const int rows     = in_sizes[0] / RANK;
    const int n_btiles = (rows + TR - 1) / TR;

    // One 64-row tile per block: HW dynamically refills CUs -> ~1-tile
    // balance granularity, no low-occupancy tail (vs 1024-persistent).
    hipLaunchKernelGGL(attn_win_kernel, dim3(n_btiles), dim3(BLOCK), 0, stream,
                       A, W, b, out, rows);
}

// Round 10
// 125.900 us; speedup vs baseline: 1.1621x; 1.1621x over previous
//
#include <hip/hip_runtime.h>
#include <hip/hip_bf16.h>

// Windowed attention smoothing via MFMA — barrier-free, per-wave autonomous.
// v8 = v5 (proven 42.4us: fp32 LDS band, bpermute M2-gather, grid=1024
// persistent, waves_per_eu(4,4)) + two verified-safe deltas:
//   1. tanh & softmax exp via v_exp_f32 (__builtin_amdgcn_exp2f) + rcp —
//      kills the 7-op fp32 divide x16 and folds the softmax scale into
//      the exp2 constant. (Correctness verified in v7b: absmax 0.015625.)
//   2. aw[26] LDS reads issued BEFORE the softmax VALU block (aw depends
//      only on the band, not Sc) — DS latency hides under softmax math.
// v7b's grid=n_btiles REVERTED: 3125 short blocks doubled WRITE_SIZE
// (100MB) and re-fetched the prologue per block (+22MB) -> 68.5us.
// v6's P4-LDS-broadcast stays REVERTED (spilled at the 64-VGPR envelope).
// No __syncthreads: LDS regions are wave-private; DS pipe is in-order
// within a wave.
//
// rows=200000, RANK=64, WINDOW=11. Block=256 (4 waves), 16 rows/wave/tile.

constexpr int RANK   = 64;
constexpr int WINDOW = 11;
constexpr int PAD    = 5;
constexpr int TILE   = 16;   // rows per wave
constexpr int BLOCK  = 256;  // 4 waves
constexpr int TR     = 64;   // rows per block-tile
constexpr int BROWS  = 28;   // staged band rows (rw-5 .. rw+22)
constexpr int BSTR   = 68;   // band row stride (floats): 272B, 16B-aligned
constexpr int SC_S   = 18;   // f32 elems per Sc row (breaks pow2)
constexpr int GRIDB  = 1024; // 4 resident blocks/CU x 256 CU (LDS-capped)

constexpr int BAND_F = BROWS * BSTR;            // 1904 floats per wave
constexpr int SC_OFF = 4 * BAND_F;              // 7616
constexpr int SMEMF  = SC_OFF + 4 * 32 * SC_S;  // 9920 floats = 39680 B

typedef short short8  __attribute__((ext_vector_type(8)));
typedef float float4v __attribute__((ext_vector_type(4)));

__device__ __forceinline__ short8 cvt_bf8(float4 a, float4 b) {
    union { short8 s; __hip_bfloat162 h[4]; } u;
    u.h[0] = __float22bfloat162_rn(make_float2(a.x, a.y));
    u.h[1] = __float22bfloat162_rn(make_float2(a.z, a.w));
    u.h[2] = __float22bfloat162_rn(make_float2(b.x, b.y));
    u.h[3] = __float22bfloat162_rn(make_float2(b.z, b.w));
    return u.s;
}

__device__ __forceinline__ float fast_tanh(float x) {
    // tanh(x) = 1 - 2/(1+e^{2x});  e^{2x} = 2^{(2*log2 e)*x}
    const float e = __builtin_amdgcn_exp2f(2.8853900817779268f * x);
    return 1.0f - 2.0f * __builtin_amdgcn_rcpf(1.0f + e);
}

__global__ __launch_bounds__(BLOCK)
__attribute__((amdgpu_waves_per_eu(4, 4)))
void attn_win_kernel(
    const float* __restrict__ A,   // (rows, 64)
    const float* __restrict__ W,   // (64, 64) row-major (out,in)
    const float* __restrict__ b,   // (64,)
    float* __restrict__ out,       // (rows, 64)
    int rows)
{
    // Flat LDS so the deliberate band-row over-reads (rows 28..31, dead
    // data) stay in-bounds of the block allocation.
    __shared__ __align__(16) float smem[SMEMF];

    const int lane = threadIdx.x & 63;
    const int wv   = threadIdx.x >> 6;
    const int m16  = lane & 15;
    const int quad = lane >> 4;
    const int sr   = lane >> 4;        // staging: row within group-of-4
    const int sc4  = (lane & 15) * 4;  // staging: col base (float4)

    float* const bandW = smem + wv * BAND_F;                 // [28][68]
    float* const ScW   = smem + SC_OFF + wv * 32 * SC_S;     // [32][18]

    // ---- Persistent W fragments (32 VGPRs) + transposed bias, loaded ONCE ----
    short8 wfrag[4][2];  // [ct][kf]: W[ct*16+m16][kf*32 + quad*8 + j]
    #pragma unroll
    for (int ct = 0; ct < 4; ct++) {
        #pragma unroll
        for (int kf = 0; kf < 2; kf++) {
            const float4* p =
                (const float4*)(W + (ct * 16 + m16) * RANK + kf * 32 + quad * 8);
            wfrag[ct][kf] = cvt_bf8(p[0], p[1]);
        }
    }
    float4 biasT[4];
    #pragma unroll
    for (int ct = 0; ct < 4; ct++)
        biasT[ct] = *(const float4*)(b + ct * 16 + quad * 4);

    // bpermute source-lane indices (byte units): word w of B-frag comes from
    // lane m16 + 16*(2*(quad&1) + (w>>1)).
    const int idxA = 4 * m16 + 128 * (quad & 1);
    const int idxB = idxA + 64;

    const int n_btiles = (rows + TR - 1) / TR;
    int bt = blockIdx.x;
    if (bt >= n_btiles) return;

    // ---- prologue: stage FIRST tile's 28-row fp32 band (guarded) ----
    {
        const int rw0 = bt * TR + wv * TILE;
        #pragma unroll
        for (int ro = 0; ro < 7; ro++) {
            const int g = rw0 - PAD + ro * 4 + sr;
            float4 x = make_float4(0.f, 0.f, 0.f, 0.f);
            if ((unsigned)g < (unsigned)rows)
                x = *(const float4*)(A + (size_t)g * RANK + sc4);
            *(float4*)&bandW[(ro * 4 + sr) * BSTR + sc4] = x;
        }
    }

    for (; bt < n_btiles; bt += gridDim.x) {
        const int rw = bt * TR + wv * TILE;   // this wave's rows rw..rw+15

        // ---- am1 frags from band (fp32 -> bf16): A rows rw+m16 ----
        short8 am1[2];
        #pragma unroll
        for (int kf = 0; kf < 2; kf++) {
            const float4* pp =
                (const float4*)&bandW[(PAD + m16) * BSTR + kf * 32 + quad * 8];
            am1[kf] = cvt_bf8(pp[0], pp[1]);
        }

        // ---- M1 (transposed): accT[ct] = W-block(ct) x A^T + b ----
        // C element: v1[m = m16][n = ct*16 + quad*4 + r]
        float4v accT[4];
        #pragma unroll
        for (int ct = 0; ct < 4; ct++)
            accT[ct] = (float4v){biasT[ct].x, biasT[ct].y,
                                 biasT[ct].z, biasT[ct].w};
        #pragma unroll
        for (int kf = 0; kf < 2; kf++)
            #pragma unroll
            for (int ct = 0; ct < 4; ct++)
                accT[ct] = __builtin_amdgcn_mfma_f32_16x16x32_bf16(
                    wfrag[ct][kf], am1[kf], accT[ct], 0, 0, 0);

        // ---- tanh + pack to bf16 pairs ----
        int pk[4][2];
        #pragma unroll
        for (int ct = 0; ct < 4; ct++)
            #pragma unroll
            for (int u = 0; u < 2; u++) {
                union { __hip_bfloat162 h; int i; } cv;
                cv.h = __float22bfloat162_rn(make_float2(
                    fast_tanh(accT[ct][2 * u]),
                    fast_tanh(accT[ct][2 * u + 1])));
                pk[ct][u] = cv.i;
            }

        // ---- M2 B-frag gather via ds_bpermute (no LDS storage) ----
        short8 bfr[2];
        #pragma unroll
        for (int kf = 0; kf < 2; kf++) {
            union { int w[4]; short8 s; } u;
            #pragma unroll
            for (int w = 0; w < 4; w++) {
                const int idx = (w >> 1) ? idxB : idxA;
                const int lo = __builtin_amdgcn_ds_bpermute(idx, pk[2 * kf][w & 1]);
                const int hi = __builtin_amdgcn_ds_bpermute(idx, pk[2 * kf + 1][w & 1]);
                u.w[w] = (quad >= 2) ? hi : lo;
            }
            bfr[kf] = u.s;
        }

        // ---- abnd frags: band rows it*16+m16 (rows 28..31 are dead reads) ----
        short8 abnd[2][2];
        #pragma unroll
        for (int it = 0; it < 2; it++)
            #pragma unroll
            for (int kf = 0; kf < 2; kf++) {
                const float4* pp = (const float4*)
                    &bandW[(it * 16 + m16) * BSTR + kf * 32 + quad * 8];
                abnd[it][kf] = cvt_bf8(pp[0], pp[1]);
            }

        // ---- issue NEXT tile's stage loads (latency hides under M2+softmax;
        //      compiler is free to place/sink — v5-proven spill-free) ----
        float4 stg[7];
        {
            const int rwn = rw + (int)gridDim.x * TR;
            #pragma unroll
            for (int ro = 0; ro < 7; ro++) {
                const int g = rwn - PAD + ro * 4 + sr;
                stg[ro] = make_float4(0.f, 0.f, 0.f, 0.f);
                if ((unsigned)g < (unsigned)rows)
                    stg[ro] = *(const float4*)(A + (size_t)g * RANK + sc4);
            }
        }

        // ---- M2: S[i][q] = dot(band[i], v1[q]) ----
        float4v sacc[2];
        sacc[0] = (float4v){0.f, 0.f, 0.f, 0.f};
        sacc[1] = (float4v){0.f, 0.f, 0.f, 0.f};
        #pragma unroll
        for (int kf = 0; kf < 2; kf++)
            #pragma unroll
            for (int it = 0; it < 2; it++)
                sacc[it] = __builtin_amdgcn_mfma_f32_16x16x32_bf16(
                    abnd[it][kf], bfr[kf], sacc[it], 0, 0, 0);

        // scatter S (i = it*16+quad*4+rg, q = m16); rows 26..31 are dead
        #pragma unroll
        for (int it = 0; it < 2; it++)
            #pragma unroll
            for (int rg = 0; rg < 4; rg++)
                ScW[(it * 16 + quad * 4 + rg) * SC_S + m16] = sacc[it][rg];

        // ---- aw: fp32 window reads issued BEFORE softmax (independent of
        //      Sc) so their DS latency hides under the softmax VALU chain ----
        float aw[26];
        #pragma unroll
        for (int s = 0; s < 26; s++) aw[s] = bandW[s * BSTR + lane];

        // ---- softmax over band i in [q, q+10] of column q=m16 ----
        // (redundant across quads; lane rr<16 holds row rw+rr's probs)
        float p[WINDOW];
        {
            float s[WINDOW];
            float mx = -1e30f;
            #pragma unroll
            for (int w = 0; w < WINDOW; w++) {
                s[w] = ScW[(m16 + w) * SC_S + m16];
                mx = fmaxf(mx, s[w]);
            }
            float den = 0.0f;
            #pragma unroll
            for (int w = 0; w < WINDOW; w++) {
                // exp((s-mx)/8) = 2^((s-mx) * 0.125*log2 e)
                p[w] = __builtin_amdgcn_exp2f(
                    (s[w] - mx) * 0.18033688011112042f);
                den += p[w];
            }
            const float rden = __fdividef(1.0f, den);
            #pragma unroll
            for (int w = 0; w < WINDOW; w++) p[w] *= rden;
        }

        // ---- overwrite band with NEXT tile's rows (DS in-order per wave;
        //      all current-band reads issued above) ----
        #pragma unroll
        for (int ro = 0; ro < 7; ro++)
            *(float4*)&bandW[(ro * 4 + sr) * BSTR + sc4] = stg[ro];

        // ---- P4: out[rw+rr][lane] = sum_w p[rr][w] * aw[rr+w] ----
        #pragma unroll
        for (int rr = 0; rr < TILE; rr++) {
            float o = 0.0f;
            #pragma unroll
            for (int w = 0; w < WINDOW; w++) {
                const float pw = __uint_as_float(
                    __builtin_amdgcn_readlane(__float_as_uint(p[w]), rr));
                o = fmaf(pw, aw[rr + w], o);
            }
            if (rw + rr < rows)   // wave-uniform scalar guard
                out[(size_t)(rw + rr) * RANK + lane] = o;
        }
    }
}

extern "C" void kernel_launch(void* const* d_in, const int* in_sizes, int n_in,
                              void* d_out, int out_size, void* d_ws, size_t ws_size,
                              hipStream_t stream) {
    const float* A = (const float*)d_in[0];
    const float* W = (const float*)d_in[1];
    const float* b = (const float*)d_in[2];
    float* out = (float*)d_out;

    const int rows     = in_sizes[0] / RANK;
    const int n_btiles = (rows + TR - 1) / TR;
    const int blocks   = n_btiles < GRIDB ? n_btiles : GRIDB;  // persistent

    hipLaunchKernelGGL(attn_win_kernel, dim3(blocks), dim3(BLOCK), 0, stream,
                       A, W, b, out, rows);
}

// Round 11
// 125.518 us; speedup vs baseline: 1.1657x; 1.0030x over previous
//
#include <hip/hip_runtime.h>
#include <hip/hip_bf16.h>

// Windowed attention smoothing via MFMA — barrier-free, per-wave autonomous.
// v9 = v5 EXACTLY (proven 42.4us: fp32 LDS band, bpermute M2-gather,
// grid=1024 persistent, waves_per_eu(4,4), v5's load/compute ordering)
// + ONE delta: tanh & softmax exp via v_exp_f32 + v_rcp_f32.
//
// Ordering lesson (4x confirmed: v1/v4/v6/v8 all spilled): the allocator
// pins 64 VGPRs; any reorder extending a >10-reg array's live range
// across a compute phase spills (+16-70MB WRITE_SIZE). So: stage loads
// stay AFTER the Sc scatter, aw reads stay AFTER softmax — v5 placement.
// No __syncthreads: LDS regions are wave-private; DS pipe is in-order
// within a wave.
//
// rows=200000, RANK=64, WINDOW=11. Block=256 (4 waves), 16 rows/wave/tile.

constexpr int RANK   = 64;
constexpr int WINDOW = 11;
constexpr int PAD    = 5;
constexpr int TILE   = 16;   // rows per wave
constexpr int BLOCK  = 256;  // 4 waves
constexpr int TR     = 64;   // rows per block-tile
constexpr int BROWS  = 28;   // staged band rows (rw-5 .. rw+22)
constexpr int BSTR   = 68;   // band row stride (floats): 272B, 16B-aligned
constexpr int SC_S   = 18;   // f32 elems per Sc row (breaks pow2)
constexpr int GRIDB  = 1024; // 4 resident blocks/CU x 256 CU (LDS-capped)

constexpr int BAND_F = BROWS * BSTR;            // 1904 floats per wave
constexpr int SC_OFF = 4 * BAND_F;              // 7616
constexpr int SMEMF  = SC_OFF + 4 * 32 * SC_S;  // 9920 floats = 39680 B

typedef short short8  __attribute__((ext_vector_type(8)));
typedef float float4v __attribute__((ext_vector_type(4)));

__device__ __forceinline__ short8 cvt_bf8(float4 a, float4 b) {
    union { short8 s; __hip_bfloat162 h[4]; } u;
    u.h[0] = __float22bfloat162_rn(make_float2(a.x, a.y));
    u.h[1] = __float22bfloat162_rn(make_float2(a.z, a.w));
    u.h[2] = __float22bfloat162_rn(make_float2(b.x, b.y));
    u.h[3] = __float22bfloat162_rn(make_float2(b.z, b.w));
    return u.s;
}

__device__ __forceinline__ float fast_tanh(float x) {
    // tanh(x) = 1 - 2/(1+e^{2x});  e^{2x} = 2^{(2*log2 e)*x}
    const float e = __builtin_amdgcn_exp2f(2.8853900817779268f * x);
    return 1.0f - 2.0f * __builtin_amdgcn_rcpf(1.0f + e);
}

__global__ __launch_bounds__(BLOCK)
__attribute__((amdgpu_waves_per_eu(4, 4)))
void attn_win_kernel(
    const float* __restrict__ A,   // (rows, 64)
    const float* __restrict__ W,   // (64, 64) row-major (out,in)
    const float* __restrict__ b,   // (64,)
    float* __restrict__ out,       // (rows, 64)
    int rows)
{
    // Flat LDS so the deliberate band-row over-reads (rows 28..31, dead
    // data) stay in-bounds of the block allocation.
    __shared__ __align__(16) float smem[SMEMF];

    const int lane = threadIdx.x & 63;
    const int wv   = threadIdx.x >> 6;
    const int m16  = lane & 15;
    const int quad = lane >> 4;
    const int sr   = lane >> 4;        // staging: row within group-of-4
    const int sc4  = (lane & 15) * 4;  // staging: col base (float4)

    float* const bandW = smem + wv * BAND_F;                 // [28][68]
    float* const ScW   = smem + SC_OFF + wv * 32 * SC_S;     // [32][18]

    // ---- Persistent W fragments (32 VGPRs) + transposed bias, loaded ONCE ----
    short8 wfrag[4][2];  // [ct][kf]: W[ct*16+m16][kf*32 + quad*8 + j]
    #pragma unroll
    for (int ct = 0; ct < 4; ct++) {
        #pragma unroll
        for (int kf = 0; kf < 2; kf++) {
            const float4* p =
                (const float4*)(W + (ct * 16 + m16) * RANK + kf * 32 + quad * 8);
            wfrag[ct][kf] = cvt_bf8(p[0], p[1]);
        }
    }
    float4 biasT[4];
    #pragma unroll
    for (int ct = 0; ct < 4; ct++)
        biasT[ct] = *(const float4*)(b + ct * 16 + quad * 4);

    // bpermute source-lane indices (byte units): word w of B-frag comes from
    // lane m16 + 16*(2*(quad&1) + (w>>1)).
    const int idxA = 4 * m16 + 128 * (quad & 1);
    const int idxB = idxA + 64;

    const int n_btiles = (rows + TR - 1) / TR;
    int bt = blockIdx.x;
    if (bt >= n_btiles) return;

    // ---- prologue: stage FIRST tile's 28-row fp32 band (guarded) ----
    {
        const int rw0 = bt * TR + wv * TILE;
        #pragma unroll
        for (int ro = 0; ro < 7; ro++) {
            const int g = rw0 - PAD + ro * 4 + sr;
            float4 x = make_float4(0.f, 0.f, 0.f, 0.f);
            if ((unsigned)g < (unsigned)rows)
                x = *(const float4*)(A + (size_t)g * RANK + sc4);
            *(float4*)&bandW[(ro * 4 + sr) * BSTR + sc4] = x;
        }
    }

    for (; bt < n_btiles; bt += gridDim.x) {
        const int rw = bt * TR + wv * TILE;   // this wave's rows rw..rw+15

        // ---- am1 frags from band (fp32 -> bf16): A rows rw+m16 ----
        short8 am1[2];
        #pragma unroll
        for (int kf = 0; kf < 2; kf++) {
            const float4* pp =
                (const float4*)&bandW[(PAD + m16) * BSTR + kf * 32 + quad * 8];
            am1[kf] = cvt_bf8(pp[0], pp[1]);
        }

        // ---- M1 (transposed): accT[ct] = W-block(ct) x A^T + b ----
        // C element: v1[m = m16][n = ct*16 + quad*4 + r]
        float4v accT[4];
        #pragma unroll
        for (int ct = 0; ct < 4; ct++)
            accT[ct] = (float4v){biasT[ct].x, biasT[ct].y,
                                 biasT[ct].z, biasT[ct].w};
        #pragma unroll
        for (int kf = 0; kf < 2; kf++)
            #pragma unroll
            for (int ct = 0; ct < 4; ct++)
                accT[ct] = __builtin_amdgcn_mfma_f32_16x16x32_bf16(
                    wfrag[ct][kf], am1[kf], accT[ct], 0, 0, 0);

        // ---- tanh + pack to bf16 pairs ----
        int pk[4][2];
        #pragma unroll
        for (int ct = 0; ct < 4; ct++)
            #pragma unroll
            for (int u = 0; u < 2; u++) {
                union { __hip_bfloat162 h; int i; } cv;
                cv.h = __float22bfloat162_rn(make_float2(
                    fast_tanh(accT[ct][2 * u]),
                    fast_tanh(accT[ct][2 * u + 1])));
                pk[ct][u] = cv.i;
            }

        // ---- M2 B-frag gather via ds_bpermute (no LDS storage) ----
        short8 bfr[2];
        #pragma unroll
        for (int kf = 0; kf < 2; kf++) {
            union { int w[4]; short8 s; } u;
            #pragma unroll
            for (int w = 0; w < 4; w++) {
                const int idx = (w >> 1) ? idxB : idxA;
                const int lo = __builtin_amdgcn_ds_bpermute(idx, pk[2 * kf][w & 1]);
                const int hi = __builtin_amdgcn_ds_bpermute(idx, pk[2 * kf + 1][w & 1]);
                u.w[w] = (quad >= 2) ? hi : lo;
            }
            bfr[kf] = u.s;
        }

        // ---- abnd frags: band rows it*16+m16 (rows 28..31 are dead reads) ----
        short8 abnd[2][2];
        #pragma unroll
        for (int it = 0; it < 2; it++)
            #pragma unroll
            for (int kf = 0; kf < 2; kf++) {
                const float4* pp = (const float4*)
                    &bandW[(it * 16 + m16) * BSTR + kf * 32 + quad * 8];
                abnd[it][kf] = cvt_bf8(pp[0], pp[1]);
            }

        // ---- issue NEXT tile's stage loads (v5 placement, spill-free) ----
        float4 stg[7];
        {
            const int rwn = rw + (int)gridDim.x * TR;
            #pragma unroll
            for (int ro = 0; ro < 7; ro++) {
                const int g = rwn - PAD + ro * 4 + sr;
                stg[ro] = make_float4(0.f, 0.f, 0.f, 0.f);
                if ((unsigned)g < (unsigned)rows)
                    stg[ro] = *(const float4*)(A + (size_t)g * RANK + sc4);
            }
        }

        // ---- M2: S[i][q] = dot(band[i], v1[q]) ----
        float4v sacc[2];
        sacc[0] = (float4v){0.f, 0.f, 0.f, 0.f};
        sacc[1] = (float4v){0.f, 0.f, 0.f, 0.f};
        #pragma unroll
        for (int kf = 0; kf < 2; kf++)
            #pragma unroll
            for (int it = 0; it < 2; it++)
                sacc[it] = __builtin_amdgcn_mfma_f32_16x16x32_bf16(
                    abnd[it][kf], bfr[kf], sacc[it], 0, 0, 0);

        // scatter S (i = it*16+quad*4+rg, q = m16); rows 26..31 are dead
        #pragma unroll
        for (int it = 0; it < 2; it++)
            #pragma unroll
            for (int rg = 0; rg < 4; rg++)
                ScW[(it * 16 + quad * 4 + rg) * SC_S + m16] = sacc[it][rg];

        // ---- softmax over band i in [q, q+10] of column q=m16 ----
        // (redundant across quads; lane rr<16 holds row rw+rr's probs)
        float p[WINDOW];
        {
            float s[WINDOW];
            float mx = -1e30f;
            #pragma unroll
            for (int w = 0; w < WINDOW; w++) {
                s[w] = ScW[(m16 + w) * SC_S + m16];
                mx = fmaxf(mx, s[w]);
            }
            float den = 0.0f;
            #pragma unroll
            for (int w = 0; w < WINDOW; w++) {
                // exp((s-mx)/8) = 2^((s-mx) * 0.125*log2 e)
                p[w] = __builtin_amdgcn_exp2f(
                    (s[w] - mx) * 0.18033688011112042f);
                den += p[w];
            }
            const float rden = __fdividef(1.0f, den);
            #pragma unroll
            for (int w = 0; w < WINDOW; w++) p[w] *= rden;
        }

        // ---- aw: fp32 window, last reads of the current band (v5 placement) ----
        float aw[26];
        #pragma unroll
        for (int s = 0; s < 26; s++) aw[s] = bandW[s * BSTR + lane];

        // ---- overwrite band with NEXT tile's rows (DS in-order per wave) ----
        #pragma unroll
        for (int ro = 0; ro < 7; ro++)
            *(float4*)&bandW[(ro * 4 + sr) * BSTR + sc4] = stg[ro];

        // ---- P4: out[rw+rr][lane] = sum_w p[rr][w] * aw[rr+w] ----
        #pragma unroll
        for (int rr = 0; rr < TILE; rr++) {
            float o = 0.0f;
            #pragma unroll
            for (int w = 0; w < WINDOW; w++) {
                const float pw = __uint_as_float(
                    __builtin_amdgcn_readlane(__float_as_uint(p[w]), rr));
                o = fmaf(pw, aw[rr + w], o);
            }
            if (rw + rr < rows)   // wave-uniform scalar guard
                out[(size_t)(rw + rr) * RANK + lane] = o;
        }
    }
}

extern "C" void kernel_launch(void* const* d_in, const int* in_sizes, int n_in,
                              void* d_out, int out_size, void* d_ws, size_t ws_size,
                              hipStream_t stream) {
    const float* A = (const float*)d_in[0];
    const float* W = (const float*)d_in[1];
    const float* b = (const float*)d_in[2];
    float* out = (float*)d_out;

    const int rows     = in_sizes[0] / RANK;
    const int n_btiles = (rows + TR - 1) / TR;
    const int blocks   = n_btiles < GRIDB ? n_btiles : GRIDB;  // persistent

    hipLaunchKernelGGL(attn_win_kernel, dim3(blocks), dim3(BLOCK), 0, stream,
                       A, W, b, out, rows);
}